// Round 14
// baseline (376.191 us; speedup 1.0000x reference)
//
#include <hip/hip_runtime.h>
#include <cstdint>

#define L_SEQ 2304
#define CDIM  512
#define NHEADS 8
#define HD    64
#define LL    ((size_t)L_SEQ * L_SEQ)
#define ROWS_TOT (16 * L_SEQ)            // 2 batches * 8 heads * L rows
#define PERBL ((size_t)2 * L_SEQ * 512)  // elems in one [2][L][512] plane

typedef short  s8v  __attribute__((ext_vector_type(8)));
typedef float  f4v  __attribute__((ext_vector_type(4)));

__device__ __forceinline__ ushort f2bf(float f) {
    union { float f; uint32_t u; } v; v.f = f;
    uint32_t u = v.u;
    uint32_t r = (u + 0x7FFFu + ((u >> 16) & 1u)) >> 16;
    return (ushort)r;
}

__device__ __forceinline__ float bf2f(ushort u) {
    union { uint32_t u; float f; } v; v.u = (uint32_t)u << 16;
    return v.f;
}

// ==================================================================
// Fused prep: blocks [0,512) convert W to fragment-major bf16 (R12);
// blocks [512,1088) do the x+pos transpose.
__global__ __launch_bounds__(256) void prep(
    const float* __restrict__ Wq, const float* __restrict__ Wk,
    const float* __restrict__ Wv, const float* __restrict__ Wo,
    const float* __restrict__ x, const float* __restrict__ pos,
    ushort* __restrict__ wf, ushort* __restrict__ xt)
{
    __shared__ ushort T[64][72];
    const int bx = blockIdx.x;
    const int t  = threadIdx.x;
    if (bx < 512) {
        const int i    = bx * 256 + t;                  // chunk id, 131072 total
        const int lane = i & 63;
        const int F    = (i >> 6) & 63;                 // ks*4 + t4
        const int ob   = (i >> 12) & 7;
        const int mat  = i >> 15;
        const float* src = (mat == 0) ? Wq : (mat == 1) ? Wk : (mat == 2) ? Wv : Wo;
        const int row = ob * 64 + (F & 3) * 16 + (lane & 15);
        const int col = (F >> 2) * 32 + (lane >> 4) * 8;
        const float4 w0 = *(const float4*)&src[(size_t)row * 512 + col];
        const float4 w1 = *(const float4*)&src[(size_t)row * 512 + col + 4];
        ushort4 o0, o1;
        o0.x = f2bf(w0.x); o0.y = f2bf(w0.y); o0.z = f2bf(w0.z); o0.w = f2bf(w0.w);
        o1.x = f2bf(w1.x); o1.y = f2bf(w1.y); o1.z = f2bf(w1.z); o1.w = f2bf(w1.w);
        *(ushort4*)&wf[(size_t)i * 8]     = o0;
        *(ushort4*)&wf[(size_t)i * 8 + 4] = o1;
    } else {
        const int bb = bx - 512;            // [0,576)
        const int l0 = (bb % 36) * 64;
        const int c0 = ((bb / 36) & 7) * 64;
        const int b  = bb / 288;
        const int cc = t >> 2;
        const int l4 = (t & 3) * 16;
        const size_t off  = ((size_t)b * CDIM + c0 + cc) * L_SEQ + l0 + l4;
        const size_t poff = (size_t)(c0 + cc) * L_SEQ + l0 + l4;
        #pragma unroll
        for (int j4 = 0; j4 < 4; j4++) {
            const float4 xv = *(const float4*)&x[off + j4 * 4];
            const float4 pv = *(const float4*)&pos[poff + j4 * 4];
            T[cc][l4 + j4 * 4 + 0] = f2bf(xv.x + pv.x);
            T[cc][l4 + j4 * 4 + 1] = f2bf(xv.y + pv.y);
            T[cc][l4 + j4 * 4 + 2] = f2bf(xv.z + pv.z);
            T[cc][l4 + j4 * 4 + 3] = f2bf(xv.w + pv.w);
        }
        __syncthreads();
        const int lr = t >> 2;
        const int c4 = (t & 3) * 16;
        ushort o[16];
        #pragma unroll
        for (int j = 0; j < 16; j++) o[j] = T[c4 + j][lr];
        ushort* dst = &xt[((size_t)b * L_SEQ + l0 + lr) * 512 + c0 + c4];
        *(ushort4*)&dst[0]  = *(ushort4*)&o[0];
        *(ushort4*)&dst[4]  = *(ushort4*)&o[4];
        *(ushort4*)&dst[8]  = *(ushort4*)&o[8];
        *(ushort4*)&dst[12] = *(ushort4*)&o[12];
    }
}

// ==================================================================
// QKV projection via bf16 MFMA, zero LDS / zero barriers, ONE MAT PER
// BLOCK: grid (36, 8, 6) -> 6912 waves (3x the merged version) to lift
// the 28% wave-starvation cap. R7 showed the merge was perf-neutral, so
// un-merging is free parallelism. block 256 (4 waves).
__global__ __launch_bounds__(256) void qkv_mfma(
    const ushort* __restrict__ xt, const ushort* __restrict__ wf,
    const float* __restrict__ bq, const float* __restrict__ bk,
    const float* __restrict__ bv,
    ushort* __restrict__ q_t, ushort* __restrict__ k_t, ushort* __restrict__ v_t)
{
    const int l0  = blockIdx.x * 64;
    const int ob  = blockIdx.y;          // o-tile = head
    const int o0  = ob * 64;
    const int mat = blockIdx.z % 3;
    const int b   = blockIdx.z / 3;
    const int t = threadIdx.x, w = t >> 6, lane = t & 63;
    const int n16 = lane & 15, q4 = lane >> 4;

    const ushort* A = xt + ((size_t)b * L_SEQ + l0 + w * 16 + n16) * 512 + q4 * 8;

    s8v areg[16];
    #pragma unroll
    for (int i = 0; i < 16; i++) areg[i] = *(const s8v*)&A[i * 32];

    const size_t lb = (size_t)lane * 8;
    const size_t wbase = (size_t)(mat * 8 + ob) * 64;

    f4v acc[4] = {{0.f,0.f,0.f,0.f},{0.f,0.f,0.f,0.f},{0.f,0.f,0.f,0.f},{0.f,0.f,0.f,0.f}};
    for (int ks = 0; ks < 16; ks++) {
        s8v bf[4];
        #pragma unroll
        for (int t4 = 0; t4 < 4; t4++)
            bf[t4] = *(const s8v*)&wf[(wbase + ks * 4 + t4) * 512 + lb];
        const s8v a = areg[ks];
        #pragma unroll
        for (int t4 = 0; t4 < 4; t4++)
            acc[t4] = __builtin_amdgcn_mfma_f32_16x16x32_bf16(a, bf[t4], acc[t4], 0, 0, 0);
    }

    const int h = ob;
    const int rowbase = l0 + w * 16 + q4 * 4;

    if (mat < 2) {
        const float* bias = (mat == 0) ? bq : bk;
        const float sc = (mat == 0) ? 0.125f : 1.0f;
        ushort* op = (mat == 0 ? q_t : k_t) + ((size_t)(b * NHEADS + h)) * L_SEQ * HD;
        #pragma unroll
        for (int t4 = 0; t4 < 4; t4++) {
            const float bi = bias[o0 + t4 * 16 + n16];
            #pragma unroll
            for (int r = 0; r < 4; r++)
                op[(size_t)(rowbase + r) * HD + t4 * 16 + n16] = f2bf((acc[t4][r] + bi) * sc);
        }
    } else {
        ushort* op = v_t + ((size_t)(b * NHEADS + h)) * HD * L_SEQ;
        #pragma unroll
        for (int t4 = 0; t4 < 4; t4++) {
            const float bi = bv[o0 + t4 * 16 + n16];
            ushort4 st;
            st.x = f2bf(acc[t4][0] + bi);
            st.y = f2bf(acc[t4][1] + bi);
            st.z = f2bf(acc[t4][2] + bi);
            st.w = f2bf(acc[t4][3] + bi);
            *(ushort4*)&op[(size_t)(t4 * 16 + n16) * L_SEQ + rowbase] = st;
        }
    }
}

// ==================================================================
// MFMA flash attention, 4-WAY SPLIT-K across blocks (2304 blocks x 9
// tiles): waves 4608 -> 9216 (29/CU) to attack the persistent ~25%
// occupancy. Single-buffered 26 KB LDS (6 blocks/CU cap, R11-proven),
// fixed-max softmax (R10), register prefetch (R11). ws_size ~650 MB
// (fill kernel evidence) so the 4-plane Opart is safe.
// grid 2304 (1D, XCD-pinned head), block 256.
__global__ __launch_bounds__(256) void flash_attn_mfma(
    const ushort* __restrict__ q, const ushort* __restrict__ k,
    const ushort* __restrict__ vt, const int* __restrict__ mask,
    const float* __restrict__ rel_table, ushort* __restrict__ Opart,
    float* __restrict__ Lpart)
{
    __shared__ __align__(16) ushort Kf[512 * 8];   // B-frags for S
    __shared__ __align__(16) ushort Vf[512 * 8];   // B-frags for PV
    __shared__ __align__(16) ushort Pb[4 * 16 * 72]; // per-wave P, [16][72]
    __shared__ float rt[65];

    const int t    = threadIdx.x;
    const int id   = blockIdx.x;
    const int h    = id & 7;            // XCD-pinned head
    const int s2   = id >> 3;           // [0,288)
    const int b    = s2 & 1;            // adjacent slots share mask rows (L2 reuse)
    const int half = (s2 >> 1) & 3;     // key quarter
    const int qb   = s2 >> 3;           // [0,36)
    const int bh   = b * NHEADS + h;
    const int l0   = qb * 64;
    const int w    = t >> 6;
    const int lane = t & 63;
    const int n16  = lane & 15;
    const int q4   = lane >> 4;

    if (t < 65) rt[t] = rel_table[h * 65 + t];

    const ushort* qp = q  + (size_t)bh * L_SEQ * HD;
    const ushort* kp = k  + (size_t)bh * L_SEQ * HD;
    const ushort* vp = vt + (size_t)bh * HD * L_SEQ;
    const int*    mp = mask + (size_t)h * LL;

    // Q A-fragments: A[m=lane&15][k=quad*8+j], rows l0+w*16+n16
    const int qrow = l0 + w * 16 + n16;
    const s8v qA0 = *(const s8v*)&qp[(size_t)qrow * HD + q4 * 8];
    const s8v qA1 = *(const s8v*)&qp[(size_t)qrow * HD + 32 + q4 * 8];

    f4v O[4] = {{0.f,0.f,0.f,0.f},{0.f,0.f,0.f,0.f},{0.f,0.f,0.f,0.f},{0.f,0.f,0.f,0.f}};
    float lrun[4] = {0.f, 0.f, 0.f, 0.f};

    // staging chunk decodes (c = t, t+256)
    int sKey[2], sD0[2], sDd[2];
    #pragma unroll
    for (int cc = 0; cc < 2; cc++) {
        const int c = t + cc * 256;
        const int g = c >> 6;
        const int sT = g >> 1, sS = g & 1;
        const int sQ = (c >> 4) & 3, sN = c & 15;
        sKey[cc] = sT * 16 + sN;
        sD0[cc]  = sS * 32 + sQ * 8;
        sDd[cc]  = sT * 16 + sN;
    }

    const int rowbase = l0 + w * 16 + q4 * 4;   // +r gives the C-layout row
    const int kbase = half * 576;

    // ---- prologue: tile 0 into registers ----
    s8v kreg[2], vreg[2];
    int mreg[4][4];
    #pragma unroll
    for (int cc = 0; cc < 2; cc++) {
        kreg[cc] = *(const s8v*)&kp[(size_t)(kbase + sKey[cc]) * HD + sD0[cc]];
        vreg[cc] = *(const s8v*)&vp[(size_t)sDd[cc] * L_SEQ + kbase + sD0[cc]];
    }
    #pragma unroll
    for (int t4 = 0; t4 < 4; t4++)
        #pragma unroll
        for (int r = 0; r < 4; r++)
            mreg[t4][r] = mp[(size_t)(rowbase + r) * L_SEQ + kbase + t4 * 16 + n16];

    for (int mt = 0; mt < 9; mt++) {
        const int mb = kbase + mt * 64;
        __syncthreads();   // WAR: previous tile's LDS reads done before restage
        #pragma unroll
        for (int cc = 0; cc < 2; cc++) {
            const int c = t + cc * 256;
            *(s8v*)&Kf[c * 8] = kreg[cc];     // vmcnt satisfied during prev compute
            *(s8v*)&Vf[c * 8] = vreg[cc];
        }
        __syncthreads();

        // ---- issue tile mt+1 loads; latency hides under this tile's compute
        const int mb2 = (mt < 8) ? mb + 64 : mb;   // clamped: always legal
        s8v knx[2], vnx[2];
        int mnx[4][4];
        #pragma unroll
        for (int cc = 0; cc < 2; cc++) {
            knx[cc] = *(const s8v*)&kp[(size_t)(mb2 + sKey[cc]) * HD + sD0[cc]];
            vnx[cc] = *(const s8v*)&vp[(size_t)sDd[cc] * L_SEQ + mb2 + sD0[cc]];
        }
        #pragma unroll
        for (int t4 = 0; t4 < 4; t4++)
            #pragma unroll
            for (int r = 0; r < 4; r++)
                mnx[t4][r] = mp[(size_t)(rowbase + r) * L_SEQ + mb2 + t4 * 16 + n16];

        // S = Q K^T  (C layout: col=lane&15 -> key t4*16+n16, row=q4*4+r)
        f4v S[4];
        #pragma unroll
        for (int t4 = 0; t4 < 4; t4++) {
            const s8v b0 = *(const s8v*)&Kf[((t4 * 2 + 0) * 64 + lane) * 8];
            const s8v b1 = *(const s8v*)&Kf[((t4 * 2 + 1) * 64 + lane) * 8];
            f4v acc = {0.f, 0.f, 0.f, 0.f};
            acc = __builtin_amdgcn_mfma_f32_16x16x32_bf16(qA0, b0, acc, 0, 0, 0);
            acc = __builtin_amdgcn_mfma_f32_16x16x32_bf16(qA1, b1, acc, 0, 0, 0);
            S[t4] = acc;
        }

        // relative positional bias (then mask -> exactly -1e9, matching ref order)
        #pragma unroll
        for (int t4 = 0; t4 < 4; t4++) {
            const int A = (l0 + w * 16) - (mb + t4 * 16);
            if (A >= 47) {
                const float bu = rt[64];
                #pragma unroll
                for (int r = 0; r < 4; r++) S[t4][r] += bu;
            } else if (A <= -47) {
                const float bu = rt[0];
                #pragma unroll
                for (int r = 0; r < 4; r++) S[t4][r] += bu;
            } else {
                #pragma unroll
                for (int r = 0; r < 4; r++) {
                    int dix = A + q4 * 4 + r - n16;
                    dix = min(max(dix, -32), 32) + 32;
                    S[t4][r] += rt[dix];
                }
            }
            #pragma unroll
            for (int r = 0; r < 4; r++)
                if (mreg[t4][r] == 0) S[t4][r] = -1e9f;
        }

        // fixed-max softmax numerator: P = exp(S) (masked -> 0)
        float sum[4] = {0.f, 0.f, 0.f, 0.f};
        #pragma unroll
        for (int r = 0; r < 4; r++) {
            #pragma unroll
            for (int t4 = 0; t4 < 4; t4++) {
                const float p = __expf(S[t4][r]);
                sum[r] += p;
                Pb[w * 1152 + (q4 * 4 + r) * 72 + t4 * 16 + n16] = f2bf(p);
            }
        }

        // O += P V   (per-wave Pb: same-wave dep, no barrier; no rescale)
        const s8v pf0 = *(const s8v*)&Pb[w * 1152 + n16 * 72 + q4 * 8];
        const s8v pf1 = *(const s8v*)&Pb[w * 1152 + n16 * 72 + 32 + q4 * 8];
        #pragma unroll
        for (int t4 = 0; t4 < 4; t4++) {
            f4v o = O[t4];
            const s8v v0 = *(const s8v*)&Vf[((t4 * 2 + 0) * 64 + lane) * 8];
            const s8v v1 = *(const s8v*)&Vf[((t4 * 2 + 1) * 64 + lane) * 8];
            o = __builtin_amdgcn_mfma_f32_16x16x32_bf16(pf0, v0, o, 0, 0, 0);
            o = __builtin_amdgcn_mfma_f32_16x16x32_bf16(pf1, v1, o, 0, 0, 0);
            O[t4] = o;
        }

        // sum reduction AFTER PV — off the MFMA critical path
        #pragma unroll
        for (int r = 0; r < 4; r++) {
            float s = sum[r];
            s += __shfl_xor(s, 1);
            s += __shfl_xor(s, 2);
            s += __shfl_xor(s, 4);
            s += __shfl_xor(s, 8);
            lrun[r] += s;
        }

        // rotate prefetched registers
        #pragma unroll
        for (int cc = 0; cc < 2; cc++) { kreg[cc] = knx[cc]; vreg[cc] = vnx[cc]; }
        #pragma unroll
        for (int t4 = 0; t4 < 4; t4++)
            #pragma unroll
            for (int r = 0; r < 4; r++)
                mreg[t4][r] = mnx[t4][r];
    }

    // write UNNORMALIZED partial O (bf16) in (b, l, c) layout + row sums
    ushort* op = Opart + (size_t)half * PERBL + (size_t)b * L_SEQ * 512;
    #pragma unroll
    for (int r = 0; r < 4; r++) {
        const size_t base = (size_t)(rowbase + r) * 512 + h * 64;
        #pragma unroll
        for (int t4 = 0; t4 < 4; t4++)
            op[base + t4 * 16 + n16] = f2bf(O[t4][r]);
    }
    if (n16 == 0) {
        const size_t sb = (size_t)half * ROWS_TOT + (size_t)bh * L_SEQ;
        #pragma unroll
        for (int r = 0; r < 4; r++)
            Lpart[sb + rowbase + r] = lrun[r];
    }
}

// ==================================================================
// Output projection via bf16 MFMA with the 4-way combine fused in:
// a = bf16((O0+O1+O2+O3) * f[head]),  f[h] = 1/sum(l). Zero LDS.
// grid (36, 8, 2), block 256.
__global__ __launch_bounds__(256) void out_mfma(
    const ushort* __restrict__ Opart, const float* __restrict__ Lp,
    const ushort* __restrict__ wf, const float* __restrict__ bo,
    const float* __restrict__ x, float* __restrict__ y)
{
    const int l0 = blockIdx.x * 64;
    const int ob = blockIdx.y;
    const int o0 = ob * 64;
    const int b  = blockIdx.z;
    const int t = threadIdx.x, w = t >> 6, lane = t & 63;
    const int n16 = lane & 15, q4 = lane >> 4;

    const int l = l0 + w * 16 + n16;      // A-row this lane holds

    // per-head normalization scales for this row
    float fsc[8];
    #pragma unroll
    for (int h = 0; h < 8; h++) {
        const size_t s = (size_t)(b * NHEADS + h) * L_SEQ + l;
        fsc[h] = 1.0f / (Lp[s] + Lp[ROWS_TOT + s] +
                         Lp[2 * (size_t)ROWS_TOT + s] + Lp[3 * (size_t)ROWS_TOT + s]);
    }

    const ushort* o0p = Opart + ((size_t)b * L_SEQ + l) * 512 + q4 * 8;

    s8v areg[16];
    #pragma unroll
    for (int ks = 0; ks < 16; ks++) {
        const float f = fsc[ks >> 1];     // head = ks>>1
        float v[8];
        #pragma unroll
        for (int j = 0; j < 8; j++) v[j] = 0.f;
        #pragma unroll
        for (int pq = 0; pq < 4; pq++) {
            const ushort4 a0 = *(const ushort4*)&o0p[(size_t)pq * PERBL + ks * 32];
            const ushort4 a1 = *(const ushort4*)&o0p[(size_t)pq * PERBL + ks * 32 + 4];
            v[0] += bf2f(a0.x); v[1] += bf2f(a0.y);
            v[2] += bf2f(a0.z); v[3] += bf2f(a0.w);
            v[4] += bf2f(a1.x); v[5] += bf2f(a1.y);
            v[6] += bf2f(a1.z); v[7] += bf2f(a1.w);
        }
        s8v a;
        #pragma unroll
        for (int j = 0; j < 8; j++) a[j] = (short)f2bf(v[j] * f);
        areg[ks] = a;
    }

    const size_t lb = (size_t)lane * 8;

    f4v acc[4] = {{0.f,0.f,0.f,0.f},{0.f,0.f,0.f,0.f},{0.f,0.f,0.f,0.f},{0.f,0.f,0.f,0.f}};
    for (int ks = 0; ks < 16; ks++) {
        s8v bf[4];
        #pragma unroll
        for (int t4 = 0; t4 < 4; t4++)
            bf[t4] = *(const s8v*)&wf[
                ((size_t)((3 * 8 + ob) * 64 + ks * 4 + t4)) * 512 + lb];
        const s8v a = areg[ks];
        #pragma unroll
        for (int t4 = 0; t4 < 4; t4++)
            acc[t4] = __builtin_amdgcn_mfma_f32_16x16x32_bf16(a, bf[t4], acc[t4], 0, 0, 0);
    }

    const int rowbase = l0 + w * 16 + q4 * 4;
    #pragma unroll
    for (int t4 = 0; t4 < 4; t4++) {
        const int o = o0 + t4 * 16 + n16;
        const float bi = bo[o];
        const size_t off = ((size_t)b * CDIM + o) * L_SEQ + rowbase;
        const float4 xv = *(const float4*)&x[off];
        float4 st;
        st.x = acc[t4][0] + bi + xv.x;
        st.y = acc[t4][1] + bi + xv.y;
        st.z = acc[t4][2] + bi + xv.z;
        st.w = acc[t4][3] + bi + xv.w;
        *(float4*)&y[off] = st;
    }
}

// ==================================================================
// LayerNorm over channels. 144 blocks, 32 positions/block (128 B
// coalesced segments), 8 channel-groups x 64 channels.
__global__ __launch_bounds__(256) void ln_kernel(
    float* __restrict__ y, const float* __restrict__ gamma,
    const float* __restrict__ beta)
{
    const int t = threadIdx.x;
    const int p = t & 31;         // position within block
    const int g = t >> 5;         // channel group: 8 groups x 64 ch
    const int pos = blockIdx.x * 32 + p;
    const int b = (pos >= L_SEQ) ? 1 : 0;
    const int l = pos - b * L_SEQ;
    float* col = y + (size_t)b * CDIM * L_SEQ + l;

    float s = 0.f, sq = 0.f;
    for (int c = g * 64; c < g * 64 + 64; c++) {
        const float v = col[(size_t)c * L_SEQ];
        s += v; sq += v * v;
    }
    __shared__ float S1[8][32];
    __shared__ float S2[8][32];
    S1[g][p] = s; S2[g][p] = sq;
    __syncthreads();
    if (t < 32) {
        float ss = 0.f, qq = 0.f;
        #pragma unroll
        for (int gg = 0; gg < 8; gg++) { ss += S1[gg][t]; qq += S2[gg][t]; }
        const float mu = ss * (1.0f / CDIM);
        const float var = qq * (1.0f / CDIM) - mu * mu;
        S1[0][t] = mu;
        S2[0][t] = rsqrtf(var + 1e-5f);
    }
    __syncthreads();
    const float mu = S1[0][p];
    const float rs = S2[0][p];
    for (int c = g * 64; c < g * 64 + 64; c++) {
        const float v = col[(size_t)c * L_SEQ];
        col[(size_t)c * L_SEQ] = (v - mu) * rs * gamma[c] + beta[c];
    }
}

// ==================================================================
extern "C" void kernel_launch(void* const* d_in, const int* in_sizes, int n_in,
                              void* d_out, int out_size, void* d_ws, size_t ws_size,
                              hipStream_t stream) {
    const float* x    = (const float*)d_in[0];
    const int* mask   = (const int*)d_in[1];
    const float* pos  = (const float*)d_in[2];
    const float* Wq   = (const float*)d_in[3];
    const float* bq   = (const float*)d_in[4];
    const float* Wk   = (const float*)d_in[5];
    const float* bk   = (const float*)d_in[6];
    const float* Wv   = (const float*)d_in[7];
    const float* bv   = (const float*)d_in[8];
    const float* Wo   = (const float*)d_in[9];
    const float* bo   = (const float*)d_in[10];
    const float* rel  = (const float*)d_in[11];
    const float* gam  = (const float*)d_in[12];
    const float* bet  = (const float*)d_in[13];

    // workspace layout (40.4 MB; ws_size ~650 MB per fill-kernel evidence):
    //   qw/kw/vw  3*PERBL ushort = 14.16 MB
    //   xtw         PERBL ushort =  4.72 MB
    //   wbw     4*512*512 ushort =  2.10 MB  (fragment-major weights)
    //   Opart     4*PERBL ushort = 18.87 MB  (bf16 partials, 4 key-quarters)
    //   Lpart   4*ROWS_TOT f32   =  0.59 MB
    ushort* qw  = (ushort*)d_ws;
    ushort* kw  = qw + PERBL;
    ushort* vw  = kw + PERBL;
    ushort* xtw = vw + PERBL;
    ushort* wbw = xtw + PERBL;
    ushort* Opart = wbw + (size_t)4 * 262144;
    float* Lpart = (float*)(Opart + 4 * PERBL);
    float* y = (float*)d_out;

    prep<<<dim3(512 + 576), 256, 0, stream>>>(Wq, Wk, Wv, Wo, x, pos, wbw, xtw);

    qkv_mfma<<<dim3(L_SEQ / 64, CDIM / 64, 6), 256, 0, stream>>>(
        xtw, wbw, bq, bk, bv, qw, kw, vw);

    flash_attn_mfma<<<dim3(2304), 256, 0, stream>>>(qw, kw, vw, mask, rel,
                                                    Opart, Lpart);

    out_mfma<<<dim3(L_SEQ / 64, CDIM / 64, 2), 256, 0, stream>>>(
        Opart, Lpart, wbw, bo, x, y);

    ln_kernel<<<(2 * L_SEQ) / 32, 256, 0, stream>>>(y, gam, bet);
}

// Round 16
// 371.469 us; speedup vs baseline: 1.0127x; 1.0127x over previous
//
#include <hip/hip_runtime.h>
#include <cstdint>

#define L_SEQ 2304
#define CDIM  512
#define NHEADS 8
#define HD    64
#define LL    ((size_t)L_SEQ * L_SEQ)
#define ROWS_TOT (16 * L_SEQ)            // 2 batches * 8 heads * L rows
#define PERBL ((size_t)2 * L_SEQ * 512)  // elems in one [2][L][512] plane

typedef short  s8v  __attribute__((ext_vector_type(8)));
typedef float  f4v  __attribute__((ext_vector_type(4)));

__device__ __forceinline__ ushort f2bf(float f) {
    union { float f; uint32_t u; } v; v.f = f;
    uint32_t u = v.u;
    uint32_t r = (u + 0x7FFFu + ((u >> 16) & 1u)) >> 16;
    return (ushort)r;
}

__device__ __forceinline__ float bf2f(ushort u) {
    union { uint32_t u; float f; } v; v.u = (uint32_t)u << 16;
    return v.f;
}

// ==================================================================
// Fused prep: blocks [0,512) convert W to fragment-major bf16 (R12);
// blocks [512,1088) do the x+pos transpose. (R13-proven.)
__global__ __launch_bounds__(256) void prep(
    const float* __restrict__ Wq, const float* __restrict__ Wk,
    const float* __restrict__ Wv, const float* __restrict__ Wo,
    const float* __restrict__ x, const float* __restrict__ pos,
    ushort* __restrict__ wf, ushort* __restrict__ xt)
{
    __shared__ ushort T[64][72];
    const int bx = blockIdx.x;
    const int t  = threadIdx.x;
    if (bx < 512) {
        const int i    = bx * 256 + t;                  // chunk id, 131072 total
        const int lane = i & 63;
        const int F    = (i >> 6) & 63;                 // ks*4 + t4
        const int ob   = (i >> 12) & 7;
        const int mat  = i >> 15;
        const float* src = (mat == 0) ? Wq : (mat == 1) ? Wk : (mat == 2) ? Wv : Wo;
        const int row = ob * 64 + (F & 3) * 16 + (lane & 15);
        const int col = (F >> 2) * 32 + (lane >> 4) * 8;
        const float4 w0 = *(const float4*)&src[(size_t)row * 512 + col];
        const float4 w1 = *(const float4*)&src[(size_t)row * 512 + col + 4];
        ushort4 o0, o1;
        o0.x = f2bf(w0.x); o0.y = f2bf(w0.y); o0.z = f2bf(w0.z); o0.w = f2bf(w0.w);
        o1.x = f2bf(w1.x); o1.y = f2bf(w1.y); o1.z = f2bf(w1.z); o1.w = f2bf(w1.w);
        *(ushort4*)&wf[(size_t)i * 8]     = o0;
        *(ushort4*)&wf[(size_t)i * 8 + 4] = o1;
    } else {
        const int bb = bx - 512;            // [0,576)
        const int l0 = (bb % 36) * 64;
        const int c0 = ((bb / 36) & 7) * 64;
        const int b  = bb / 288;
        const int cc = t >> 2;
        const int l4 = (t & 3) * 16;
        const size_t off  = ((size_t)b * CDIM + c0 + cc) * L_SEQ + l0 + l4;
        const size_t poff = (size_t)(c0 + cc) * L_SEQ + l0 + l4;
        #pragma unroll
        for (int j4 = 0; j4 < 4; j4++) {
            const float4 xv = *(const float4*)&x[off + j4 * 4];
            const float4 pv = *(const float4*)&pos[poff + j4 * 4];
            T[cc][l4 + j4 * 4 + 0] = f2bf(xv.x + pv.x);
            T[cc][l4 + j4 * 4 + 1] = f2bf(xv.y + pv.y);
            T[cc][l4 + j4 * 4 + 2] = f2bf(xv.z + pv.z);
            T[cc][l4 + j4 * 4 + 3] = f2bf(xv.w + pv.w);
        }
        __syncthreads();
        const int lr = t >> 2;
        const int c4 = (t & 3) * 16;
        ushort o[16];
        #pragma unroll
        for (int j = 0; j < 16; j++) o[j] = T[c4 + j][lr];
        ushort* dst = &xt[((size_t)b * L_SEQ + l0 + lr) * 512 + c0 + c4];
        *(ushort4*)&dst[0]  = *(ushort4*)&o[0];
        *(ushort4*)&dst[4]  = *(ushort4*)&o[4];
        *(ushort4*)&dst[8]  = *(ushort4*)&o[8];
        *(ushort4*)&dst[12] = *(ushort4*)&o[12];
    }
}

// ==================================================================
// QKV projection via bf16 MFMA, zero LDS / zero barriers, ALL 3 MATS
// per block (R13-proven; R14's un-merge cost ~13 us). grid (36, 8, 2).
__global__ __launch_bounds__(256) void qkv_mfma(
    const ushort* __restrict__ xt, const ushort* __restrict__ wf,
    const float* __restrict__ bq, const float* __restrict__ bk,
    const float* __restrict__ bv,
    ushort* __restrict__ q_t, ushort* __restrict__ k_t, ushort* __restrict__ v_t)
{
    const int l0 = blockIdx.x * 64;
    const int ob = blockIdx.y;          // o-tile = head
    const int o0 = ob * 64;
    const int b  = blockIdx.z;
    const int t = threadIdx.x, w = t >> 6, lane = t & 63;
    const int n16 = lane & 15, q4 = lane >> 4;

    const ushort* A = xt + ((size_t)b * L_SEQ + l0 + w * 16 + n16) * 512 + q4 * 8;

    s8v areg[16];
    #pragma unroll
    for (int i = 0; i < 16; i++) areg[i] = *(const s8v*)&A[i * 32];

    const size_t lb = (size_t)lane * 8;

    f4v acc[3][4] = {};
    for (int ks = 0; ks < 16; ks++) {
        s8v bf[3][4];
        #pragma unroll
        for (int m = 0; m < 3; m++)
            #pragma unroll
            for (int t4 = 0; t4 < 4; t4++)
                bf[m][t4] = *(const s8v*)&wf[
                    ((size_t)((m * 8 + ob) * 64 + ks * 4 + t4)) * 512 + lb];
        const s8v a = areg[ks];
        #pragma unroll
        for (int m = 0; m < 3; m++)
            #pragma unroll
            for (int t4 = 0; t4 < 4; t4++)
                acc[m][t4] = __builtin_amdgcn_mfma_f32_16x16x32_bf16(a, bf[m][t4], acc[m][t4], 0, 0, 0);
    }

    const int h = ob;
    const int rowbase = l0 + w * 16 + q4 * 4;

    #pragma unroll
    for (int m = 0; m < 2; m++) {
        const float* bias = (m == 0) ? bq : bk;
        const float sc = (m == 0) ? 0.125f : 1.0f;
        ushort* op = (m == 0 ? q_t : k_t) + ((size_t)(b * NHEADS + h)) * L_SEQ * HD;
        #pragma unroll
        for (int t4 = 0; t4 < 4; t4++) {
            const float bi = bias[o0 + t4 * 16 + n16];
            #pragma unroll
            for (int r = 0; r < 4; r++)
                op[(size_t)(rowbase + r) * HD + t4 * 16 + n16] = f2bf((acc[m][t4][r] + bi) * sc);
        }
    }
    {
        ushort* op = v_t + ((size_t)(b * NHEADS + h)) * HD * L_SEQ;
        #pragma unroll
        for (int t4 = 0; t4 < 4; t4++) {
            const float bi = bv[o0 + t4 * 16 + n16];
            ushort4 st;
            st.x = f2bf(acc[2][t4][0] + bi);
            st.y = f2bf(acc[2][t4][1] + bi);
            st.z = f2bf(acc[2][t4][2] + bi);
            st.w = f2bf(acc[2][t4][3] + bi);
            *(ushort4*)&op[(size_t)(t4 * 16 + n16) * L_SEQ + rowbase] = st;
        }
    }
}

// ==================================================================
// MFMA flash attention, 4-way split-K (R14-proven: 97.5 vs 104 us),
// single-buffered 26 KB LDS, fixed-max softmax (R10), register
// prefetch (R11). grid 2304 (1D, XCD-pinned head), block 256.
__global__ __launch_bounds__(256) void flash_attn_mfma(
    const ushort* __restrict__ q, const ushort* __restrict__ k,
    const ushort* __restrict__ vt, const int* __restrict__ mask,
    const float* __restrict__ rel_table, ushort* __restrict__ Opart,
    float* __restrict__ Lpart)
{
    __shared__ __align__(16) ushort Kf[512 * 8];   // B-frags for S
    __shared__ __align__(16) ushort Vf[512 * 8];   // B-frags for PV
    __shared__ __align__(16) ushort Pb[4 * 16 * 72]; // per-wave P, [16][72]
    __shared__ float rt[65];

    const int t    = threadIdx.x;
    const int id   = blockIdx.x;
    const int h    = id & 7;            // XCD-pinned head
    const int s2   = id >> 3;           // [0,288)
    const int b    = s2 & 1;            // adjacent slots share mask rows (L2 reuse)
    const int half = (s2 >> 1) & 3;     // key quarter
    const int qb   = s2 >> 3;           // [0,36)
    const int bh   = b * NHEADS + h;
    const int l0   = qb * 64;
    const int w    = t >> 6;
    const int lane = t & 63;
    const int n16  = lane & 15;
    const int q4   = lane >> 4;

    if (t < 65) rt[t] = rel_table[h * 65 + t];

    const ushort* qp = q  + (size_t)bh * L_SEQ * HD;
    const ushort* kp = k  + (size_t)bh * L_SEQ * HD;
    const ushort* vp = vt + (size_t)bh * HD * L_SEQ;
    const int*    mp = mask + (size_t)h * LL;

    // Q A-fragments: A[m=lane&15][k=quad*8+j], rows l0+w*16+n16
    const int qrow = l0 + w * 16 + n16;
    const s8v qA0 = *(const s8v*)&qp[(size_t)qrow * HD + q4 * 8];
    const s8v qA1 = *(const s8v*)&qp[(size_t)qrow * HD + 32 + q4 * 8];

    f4v O[4] = {{0.f,0.f,0.f,0.f},{0.f,0.f,0.f,0.f},{0.f,0.f,0.f,0.f},{0.f,0.f,0.f,0.f}};
    float lrun[4] = {0.f, 0.f, 0.f, 0.f};

    // staging chunk decodes (c = t, t+256)
    int sKey[2], sD0[2], sDd[2];
    #pragma unroll
    for (int cc = 0; cc < 2; cc++) {
        const int c = t + cc * 256;
        const int g = c >> 6;
        const int sT = g >> 1, sS = g & 1;
        const int sQ = (c >> 4) & 3, sN = c & 15;
        sKey[cc] = sT * 16 + sN;
        sD0[cc]  = sS * 32 + sQ * 8;
        sDd[cc]  = sT * 16 + sN;
    }

    const int rowbase = l0 + w * 16 + q4 * 4;   // +r gives the C-layout row
    const int kbase = half * 576;

    // ---- prologue: tile 0 into registers ----
    s8v kreg[2], vreg[2];
    int mreg[4][4];
    #pragma unroll
    for (int cc = 0; cc < 2; cc++) {
        kreg[cc] = *(const s8v*)&kp[(size_t)(kbase + sKey[cc]) * HD + sD0[cc]];
        vreg[cc] = *(const s8v*)&vp[(size_t)sDd[cc] * L_SEQ + kbase + sD0[cc]];
    }
    #pragma unroll
    for (int t4 = 0; t4 < 4; t4++)
        #pragma unroll
        for (int r = 0; r < 4; r++)
            mreg[t4][r] = mp[(size_t)(rowbase + r) * L_SEQ + kbase + t4 * 16 + n16];

    for (int mt = 0; mt < 9; mt++) {
        const int mb = kbase + mt * 64;
        __syncthreads();   // WAR: previous tile's LDS reads done before restage
        #pragma unroll
        for (int cc = 0; cc < 2; cc++) {
            const int c = t + cc * 256;
            *(s8v*)&Kf[c * 8] = kreg[cc];     // vmcnt satisfied during prev compute
            *(s8v*)&Vf[c * 8] = vreg[cc];
        }
        __syncthreads();

        // ---- issue tile mt+1 loads; latency hides under this tile's compute
        const int mb2 = (mt < 8) ? mb + 64 : mb;   // clamped: always legal
        s8v knx[2], vnx[2];
        int mnx[4][4];
        #pragma unroll
        for (int cc = 0; cc < 2; cc++) {
            knx[cc] = *(const s8v*)&kp[(size_t)(mb2 + sKey[cc]) * HD + sD0[cc]];
            vnx[cc] = *(const s8v*)&vp[(size_t)sDd[cc] * L_SEQ + mb2 + sD0[cc]];
        }
        #pragma unroll
        for (int t4 = 0; t4 < 4; t4++)
            #pragma unroll
            for (int r = 0; r < 4; r++)
                mnx[t4][r] = mp[(size_t)(rowbase + r) * L_SEQ + mb2 + t4 * 16 + n16];

        // S = Q K^T  (C layout: col=lane&15 -> key t4*16+n16, row=q4*4+r)
        f4v S[4];
        #pragma unroll
        for (int t4 = 0; t4 < 4; t4++) {
            const s8v b0 = *(const s8v*)&Kf[((t4 * 2 + 0) * 64 + lane) * 8];
            const s8v b1 = *(const s8v*)&Kf[((t4 * 2 + 1) * 64 + lane) * 8];
            f4v acc = {0.f, 0.f, 0.f, 0.f};
            acc = __builtin_amdgcn_mfma_f32_16x16x32_bf16(qA0, b0, acc, 0, 0, 0);
            acc = __builtin_amdgcn_mfma_f32_16x16x32_bf16(qA1, b1, acc, 0, 0, 0);
            S[t4] = acc;
        }

        // relative positional bias (then mask -> exactly -1e9, matching ref order)
        #pragma unroll
        for (int t4 = 0; t4 < 4; t4++) {
            const int A = (l0 + w * 16) - (mb + t4 * 16);
            if (A >= 47) {
                const float bu = rt[64];
                #pragma unroll
                for (int r = 0; r < 4; r++) S[t4][r] += bu;
            } else if (A <= -47) {
                const float bu = rt[0];
                #pragma unroll
                for (int r = 0; r < 4; r++) S[t4][r] += bu;
            } else {
                #pragma unroll
                for (int r = 0; r < 4; r++) {
                    int dix = A + q4 * 4 + r - n16;
                    dix = min(max(dix, -32), 32) + 32;
                    S[t4][r] += rt[dix];
                }
            }
            #pragma unroll
            for (int r = 0; r < 4; r++)
                if (mreg[t4][r] == 0) S[t4][r] = -1e9f;
        }

        // fixed-max softmax numerator: P = exp(S) (masked -> 0)
        float sum[4] = {0.f, 0.f, 0.f, 0.f};
        #pragma unroll
        for (int r = 0; r < 4; r++) {
            #pragma unroll
            for (int t4 = 0; t4 < 4; t4++) {
                const float p = __expf(S[t4][r]);
                sum[r] += p;
                Pb[w * 1152 + (q4 * 4 + r) * 72 + t4 * 16 + n16] = f2bf(p);
            }
        }

        // O += P V   (per-wave Pb: same-wave dep, no barrier; no rescale)
        const s8v pf0 = *(const s8v*)&Pb[w * 1152 + n16 * 72 + q4 * 8];
        const s8v pf1 = *(const s8v*)&Pb[w * 1152 + n16 * 72 + 32 + q4 * 8];
        #pragma unroll
        for (int t4 = 0; t4 < 4; t4++) {
            f4v o = O[t4];
            const s8v v0 = *(const s8v*)&Vf[((t4 * 2 + 0) * 64 + lane) * 8];
            const s8v v1 = *(const s8v*)&Vf[((t4 * 2 + 1) * 64 + lane) * 8];
            o = __builtin_amdgcn_mfma_f32_16x16x32_bf16(pf0, v0, o, 0, 0, 0);
            o = __builtin_amdgcn_mfma_f32_16x16x32_bf16(pf1, v1, o, 0, 0, 0);
            O[t4] = o;
        }

        // sum reduction AFTER PV — off the MFMA critical path
        #pragma unroll
        for (int r = 0; r < 4; r++) {
            float s = sum[r];
            s += __shfl_xor(s, 1);
            s += __shfl_xor(s, 2);
            s += __shfl_xor(s, 4);
            s += __shfl_xor(s, 8);
            lrun[r] += s;
        }

        // rotate prefetched registers
        #pragma unroll
        for (int cc = 0; cc < 2; cc++) { kreg[cc] = knx[cc]; vreg[cc] = vnx[cc]; }
        #pragma unroll
        for (int t4 = 0; t4 < 4; t4++)
            #pragma unroll
            for (int r = 0; r < 4; r++)
                mreg[t4][r] = mnx[t4][r];
    }

    // write UNNORMALIZED partial O (bf16) in (b, l, c) layout + row sums
    ushort* op = Opart + (size_t)half * PERBL + (size_t)b * L_SEQ * 512;
    #pragma unroll
    for (int r = 0; r < 4; r++) {
        const size_t base = (size_t)(rowbase + r) * 512 + h * 64;
        #pragma unroll
        for (int t4 = 0; t4 < 4; t4++)
            op[base + t4 * 16 + n16] = f2bf(O[t4][r]);
    }
    if (n16 == 0) {
        const size_t sb = (size_t)half * ROWS_TOT + (size_t)bh * L_SEQ;
        #pragma unroll
        for (int r = 0; r < 4; r++)
            Lpart[sb + rowbase + r] = lrun[r];
    }
}

// ==================================================================
// Output projection via bf16 MFMA with the 4-way combine fused in:
// a = bf16((O0+O1+O2+O3) * f[head]),  f[h] = 1/sum(l). Zero LDS.
// grid (36, 8, 2), block 256.
__global__ __launch_bounds__(256) void out_mfma(
    const ushort* __restrict__ Opart, const float* __restrict__ Lp,
    const ushort* __restrict__ wf, const float* __restrict__ bo,
    const float* __restrict__ x, float* __restrict__ y)
{
    const int l0 = blockIdx.x * 64;
    const int ob = blockIdx.y;
    const int o0 = ob * 64;
    const int b  = blockIdx.z;
    const int t = threadIdx.x, w = t >> 6, lane = t & 63;
    const int n16 = lane & 15, q4 = lane >> 4;

    const int l = l0 + w * 16 + n16;      // A-row this lane holds

    // per-head normalization scales for this row
    float fsc[8];
    #pragma unroll
    for (int h = 0; h < 8; h++) {
        const size_t s = (size_t)(b * NHEADS + h) * L_SEQ + l;
        fsc[h] = 1.0f / (Lp[s] + Lp[ROWS_TOT + s] +
                         Lp[2 * (size_t)ROWS_TOT + s] + Lp[3 * (size_t)ROWS_TOT + s]);
    }

    const ushort* o0p = Opart + ((size_t)b * L_SEQ + l) * 512 + q4 * 8;

    s8v areg[16];
    #pragma unroll
    for (int ks = 0; ks < 16; ks++) {
        const float f = fsc[ks >> 1];     // head = ks>>1
        float v[8];
        #pragma unroll
        for (int j = 0; j < 8; j++) v[j] = 0.f;
        #pragma unroll
        for (int pq = 0; pq < 4; pq++) {
            const ushort4 a0 = *(const ushort4*)&o0p[(size_t)pq * PERBL + ks * 32];
            const ushort4 a1 = *(const ushort4*)&o0p[(size_t)pq * PERBL + ks * 32 + 4];
            v[0] += bf2f(a0.x); v[1] += bf2f(a0.y);
            v[2] += bf2f(a0.z); v[3] += bf2f(a0.w);
            v[4] += bf2f(a1.x); v[5] += bf2f(a1.y);
            v[6] += bf2f(a1.z); v[7] += bf2f(a1.w);
        }
        s8v a;
        #pragma unroll
        for (int j = 0; j < 8; j++) a[j] = (short)f2bf(v[j] * f);
        areg[ks] = a;
    }

    const size_t lb = (size_t)lane * 8;

    f4v acc[4] = {{0.f,0.f,0.f,0.f},{0.f,0.f,0.f,0.f},{0.f,0.f,0.f,0.f},{0.f,0.f,0.f,0.f}};
    for (int ks = 0; ks < 16; ks++) {
        s8v bf[4];
        #pragma unroll
        for (int t4 = 0; t4 < 4; t4++)
            bf[t4] = *(const s8v*)&wf[
                ((size_t)((3 * 8 + ob) * 64 + ks * 4 + t4)) * 512 + lb];
        const s8v a = areg[ks];
        #pragma unroll
        for (int t4 = 0; t4 < 4; t4++)
            acc[t4] = __builtin_amdgcn_mfma_f32_16x16x32_bf16(a, bf[t4], acc[t4], 0, 0, 0);
    }

    const int rowbase = l0 + w * 16 + q4 * 4;
    #pragma unroll
    for (int t4 = 0; t4 < 4; t4++) {
        const int o = o0 + t4 * 16 + n16;
        const float bi = bo[o];
        const size_t off = ((size_t)b * CDIM + o) * L_SEQ + rowbase;
        const float4 xv = *(const float4*)&x[off];
        float4 st;
        st.x = acc[t4][0] + bi + xv.x;
        st.y = acc[t4][1] + bi + xv.y;
        st.z = acc[t4][2] + bi + xv.z;
        st.w = acc[t4][3] + bi + xv.w;
        *(float4*)&y[off] = st;
    }
}

// ==================================================================
// LayerNorm over channels. 144 blocks, 32 positions/block (128 B
// coalesced segments), 8 channel-groups x 64 channels.
__global__ __launch_bounds__(256) void ln_kernel(
    float* __restrict__ y, const float* __restrict__ gamma,
    const float* __restrict__ beta)
{
    const int t = threadIdx.x;
    const int p = t & 31;         // position within block
    const int g = t >> 5;         // channel group: 8 groups x 64 ch
    const int pos = blockIdx.x * 32 + p;
    const int b = (pos >= L_SEQ) ? 1 : 0;
    const int l = pos - b * L_SEQ;
    float* col = y + (size_t)b * CDIM * L_SEQ + l;

    float s = 0.f, sq = 0.f;
    for (int c = g * 64; c < g * 64 + 64; c++) {
        const float v = col[(size_t)c * L_SEQ];
        s += v; sq += v * v;
    }
    __shared__ float S1[8][32];
    __shared__ float S2[8][32];
    S1[g][p] = s; S2[g][p] = sq;
    __syncthreads();
    if (t < 32) {
        float ss = 0.f, qq = 0.f;
        #pragma unroll
        for (int gg = 0; gg < 8; gg++) { ss += S1[gg][t]; qq += S2[gg][t]; }
        const float mu = ss * (1.0f / CDIM);
        const float var = qq * (1.0f / CDIM) - mu * mu;
        S1[0][t] = mu;
        S2[0][t] = rsqrtf(var + 1e-5f);
    }
    __syncthreads();
    const float mu = S1[0][p];
    const float rs = S2[0][p];
    for (int c = g * 64; c < g * 64 + 64; c++) {
        const float v = col[(size_t)c * L_SEQ];
        col[(size_t)c * L_SEQ] = (v - mu) * rs * gamma[c] + beta[c];
    }
}

// ==================================================================
extern "C" void kernel_launch(void* const* d_in, const int* in_sizes, int n_in,
                              void* d_out, int out_size, void* d_ws, size_t ws_size,
                              hipStream_t stream) {
    const float* x    = (const float*)d_in[0];
    const int* mask   = (const int*)d_in[1];
    const float* pos  = (const float*)d_in[2];
    const float* Wq   = (const float*)d_in[3];
    const float* bq   = (const float*)d_in[4];
    const float* Wk   = (const float*)d_in[5];
    const float* bk   = (const float*)d_in[6];
    const float* Wv   = (const float*)d_in[7];
    const float* bv   = (const float*)d_in[8];
    const float* Wo   = (const float*)d_in[9];
    const float* bo   = (const float*)d_in[10];
    const float* rel  = (const float*)d_in[11];
    const float* gam  = (const float*)d_in[12];
    const float* bet  = (const float*)d_in[13];

    // workspace layout (40.4 MB; ws_size ~650 MB per fill-kernel evidence):
    //   qw/kw/vw  3*PERBL ushort = 14.16 MB
    //   xtw         PERBL ushort =  4.72 MB
    //   wbw     4*512*512 ushort =  2.10 MB  (fragment-major weights)
    //   Opart     4*PERBL ushort = 18.87 MB  (bf16 partials, 4 key-quarters)
    //   Lpart   4*ROWS_TOT f32   =  0.59 MB
    ushort* qw  = (ushort*)d_ws;
    ushort* kw  = qw + PERBL;
    ushort* vw  = kw + PERBL;
    ushort* xtw = vw + PERBL;
    ushort* wbw = xtw + PERBL;
    ushort* Opart = wbw + (size_t)4 * 262144;
    float* Lpart = (float*)(Opart + 4 * PERBL);
    float* y = (float*)d_out;

    prep<<<dim3(512 + 576), 256, 0, stream>>>(Wq, Wk, Wv, Wo, x, pos, wbw, xtw);

    qkv_mfma<<<dim3(L_SEQ / 64, CDIM / 64, 2), 256, 0, stream>>>(
        xtw, wbw, bq, bk, bv, qw, kw, vw);

    flash_attn_mfma<<<dim3(2304), 256, 0, stream>>>(qw, kw, vw, mask, rel,
                                                    Opart, Lpart);

    out_mfma<<<dim3(L_SEQ / 64, CDIM / 64, 2), 256, 0, stream>>>(
        Opart, Lpart, wbw, bo, x, y);

    ln_kernel<<<(2 * L_SEQ) / 32, 256, 0, stream>>>(y, gam, bet);
}

// Round 17
// 365.161 us; speedup vs baseline: 1.0302x; 1.0173x over previous
//
#include <hip/hip_runtime.h>
#include <cstdint>

#define L_SEQ 2304
#define CDIM  512
#define NHEADS 8
#define HD    64
#define LL    ((size_t)L_SEQ * L_SEQ)
#define ROWS_TOT (16 * L_SEQ)            // 2 batches * 8 heads * L rows
#define PERBL ((size_t)2 * L_SEQ * 512)  // elems in one [2][L][512] plane

typedef short  s8v  __attribute__((ext_vector_type(8)));
typedef float  f4v  __attribute__((ext_vector_type(4)));

__device__ __forceinline__ ushort f2bf(float f) {
    union { float f; uint32_t u; } v; v.f = f;
    uint32_t u = v.u;
    uint32_t r = (u + 0x7FFFu + ((u >> 16) & 1u)) >> 16;
    return (ushort)r;
}

__device__ __forceinline__ float bf2f(ushort u) {
    union { uint32_t u; float f; } v; v.u = (uint32_t)u << 16;
    return v.f;
}

// ==================================================================
// Fused prep: blocks [0,512) convert W to fragment-major bf16 (R12);
// blocks [512,1088) do the x+pos transpose. (R13-proven.)
__global__ __launch_bounds__(256) void prep(
    const float* __restrict__ Wq, const float* __restrict__ Wk,
    const float* __restrict__ Wv, const float* __restrict__ Wo,
    const float* __restrict__ x, const float* __restrict__ pos,
    ushort* __restrict__ wf, ushort* __restrict__ xt)
{
    __shared__ ushort T[64][72];
    const int bx = blockIdx.x;
    const int t  = threadIdx.x;
    if (bx < 512) {
        const int i    = bx * 256 + t;                  // chunk id, 131072 total
        const int lane = i & 63;
        const int F    = (i >> 6) & 63;                 // ks*4 + t4
        const int ob   = (i >> 12) & 7;
        const int mat  = i >> 15;
        const float* src = (mat == 0) ? Wq : (mat == 1) ? Wk : (mat == 2) ? Wv : Wo;
        const int row = ob * 64 + (F & 3) * 16 + (lane & 15);
        const int col = (F >> 2) * 32 + (lane >> 4) * 8;
        const float4 w0 = *(const float4*)&src[(size_t)row * 512 + col];
        const float4 w1 = *(const float4*)&src[(size_t)row * 512 + col + 4];
        ushort4 o0, o1;
        o0.x = f2bf(w0.x); o0.y = f2bf(w0.y); o0.z = f2bf(w0.z); o0.w = f2bf(w0.w);
        o1.x = f2bf(w1.x); o1.y = f2bf(w1.y); o1.z = f2bf(w1.z); o1.w = f2bf(w1.w);
        *(ushort4*)&wf[(size_t)i * 8]     = o0;
        *(ushort4*)&wf[(size_t)i * 8 + 4] = o1;
    } else {
        const int bb = bx - 512;            // [0,576)
        const int l0 = (bb % 36) * 64;
        const int c0 = ((bb / 36) & 7) * 64;
        const int b  = bb / 288;
        const int cc = t >> 2;
        const int l4 = (t & 3) * 16;
        const size_t off  = ((size_t)b * CDIM + c0 + cc) * L_SEQ + l0 + l4;
        const size_t poff = (size_t)(c0 + cc) * L_SEQ + l0 + l4;
        #pragma unroll
        for (int j4 = 0; j4 < 4; j4++) {
            const float4 xv = *(const float4*)&x[off + j4 * 4];
            const float4 pv = *(const float4*)&pos[poff + j4 * 4];
            T[cc][l4 + j4 * 4 + 0] = f2bf(xv.x + pv.x);
            T[cc][l4 + j4 * 4 + 1] = f2bf(xv.y + pv.y);
            T[cc][l4 + j4 * 4 + 2] = f2bf(xv.z + pv.z);
            T[cc][l4 + j4 * 4 + 3] = f2bf(xv.w + pv.w);
        }
        __syncthreads();
        const int lr = t >> 2;
        const int c4 = (t & 3) * 16;
        ushort o[16];
        #pragma unroll
        for (int j = 0; j < 16; j++) o[j] = T[c4 + j][lr];
        ushort* dst = &xt[((size_t)b * L_SEQ + l0 + lr) * 512 + c0 + c4];
        *(ushort4*)&dst[0]  = *(ushort4*)&o[0];
        *(ushort4*)&dst[4]  = *(ushort4*)&o[4];
        *(ushort4*)&dst[8]  = *(ushort4*)&o[8];
        *(ushort4*)&dst[12] = *(ushort4*)&o[12];
    }
}

// ==================================================================
// QKV projection via bf16 MFMA, zero LDS / zero barriers, ALL 3 MATS
// per block (R13-proven; R14's un-merge cost ~13 us). grid (36, 8, 2).
__global__ __launch_bounds__(256) void qkv_mfma(
    const ushort* __restrict__ xt, const ushort* __restrict__ wf,
    const float* __restrict__ bq, const float* __restrict__ bk,
    const float* __restrict__ bv,
    ushort* __restrict__ q_t, ushort* __restrict__ k_t, ushort* __restrict__ v_t)
{
    const int l0 = blockIdx.x * 64;
    const int ob = blockIdx.y;          // o-tile = head
    const int o0 = ob * 64;
    const int b  = blockIdx.z;
    const int t = threadIdx.x, w = t >> 6, lane = t & 63;
    const int n16 = lane & 15, q4 = lane >> 4;

    const ushort* A = xt + ((size_t)b * L_SEQ + l0 + w * 16 + n16) * 512 + q4 * 8;

    s8v areg[16];
    #pragma unroll
    for (int i = 0; i < 16; i++) areg[i] = *(const s8v*)&A[i * 32];

    const size_t lb = (size_t)lane * 8;

    f4v acc[3][4] = {};
    for (int ks = 0; ks < 16; ks++) {
        s8v bf[3][4];
        #pragma unroll
        for (int m = 0; m < 3; m++)
            #pragma unroll
            for (int t4 = 0; t4 < 4; t4++)
                bf[m][t4] = *(const s8v*)&wf[
                    ((size_t)((m * 8 + ob) * 64 + ks * 4 + t4)) * 512 + lb];
        const s8v a = areg[ks];
        #pragma unroll
        for (int m = 0; m < 3; m++)
            #pragma unroll
            for (int t4 = 0; t4 < 4; t4++)
                acc[m][t4] = __builtin_amdgcn_mfma_f32_16x16x32_bf16(a, bf[m][t4], acc[m][t4], 0, 0, 0);
    }

    const int h = ob;
    const int rowbase = l0 + w * 16 + q4 * 4;

    #pragma unroll
    for (int m = 0; m < 2; m++) {
        const float* bias = (m == 0) ? bq : bk;
        const float sc = (m == 0) ? 0.125f : 1.0f;
        ushort* op = (m == 0 ? q_t : k_t) + ((size_t)(b * NHEADS + h)) * L_SEQ * HD;
        #pragma unroll
        for (int t4 = 0; t4 < 4; t4++) {
            const float bi = bias[o0 + t4 * 16 + n16];
            #pragma unroll
            for (int r = 0; r < 4; r++)
                op[(size_t)(rowbase + r) * HD + t4 * 16 + n16] = f2bf((acc[m][t4][r] + bi) * sc);
        }
    }
    {
        ushort* op = v_t + ((size_t)(b * NHEADS + h)) * HD * L_SEQ;
        #pragma unroll
        for (int t4 = 0; t4 < 4; t4++) {
            const float bi = bv[o0 + t4 * 16 + n16];
            ushort4 st;
            st.x = f2bf(acc[2][t4][0] + bi);
            st.y = f2bf(acc[2][t4][1] + bi);
            st.z = f2bf(acc[2][t4][2] + bi);
            st.w = f2bf(acc[2][t4][3] + bi);
            *(ushort4*)&op[(size_t)(t4 * 16 + n16) * L_SEQ + rowbase] = st;
        }
    }
}

// ==================================================================
// MFMA flash attention — R12's proven-fastest flash variant (100.5 us):
// 2-way split-K (1152 blocks x 18 tiles), SINGLE-buffered 26 KB LDS
// (6 blocks/CU cap), two barriers/tile, fixed-max softmax (R10),
// register prefetch (R11). R13's dbuf (42.5 KB) measured SLOWER (104.5)
// and R16's 4-way split forces the expensive 4-way out-combine.
// grid 1152 (1D, XCD-pinned head), block 256.
__global__ __launch_bounds__(256) void flash_attn_mfma(
    const ushort* __restrict__ q, const ushort* __restrict__ k,
    const ushort* __restrict__ vt, const int* __restrict__ mask,
    const float* __restrict__ rel_table, ushort* __restrict__ Opart,
    float* __restrict__ Lpart)
{
    __shared__ __align__(16) ushort Kf[512 * 8];   // B-frags for S
    __shared__ __align__(16) ushort Vf[512 * 8];   // B-frags for PV
    __shared__ __align__(16) ushort Pb[4 * 16 * 72]; // per-wave P, [16][72]
    __shared__ float rt[65];

    const int t    = threadIdx.x;
    const int id   = blockIdx.x;
    const int h    = id & 7;            // XCD-pinned head
    const int s2   = id >> 3;           // [0,144)
    const int b    = s2 & 1;            // adjacent slots share mask rows (L2 reuse)
    const int half = (s2 >> 1) & 1;     // key half
    const int qb   = s2 >> 2;           // [0,36)
    const int bh   = b * NHEADS + h;
    const int l0   = qb * 64;
    const int w    = t >> 6;
    const int lane = t & 63;
    const int n16  = lane & 15;
    const int q4   = lane >> 4;

    if (t < 65) rt[t] = rel_table[h * 65 + t];

    const ushort* qp = q  + (size_t)bh * L_SEQ * HD;
    const ushort* kp = k  + (size_t)bh * L_SEQ * HD;
    const ushort* vp = vt + (size_t)bh * HD * L_SEQ;
    const int*    mp = mask + (size_t)h * LL;

    // Q A-fragments: A[m=lane&15][k=quad*8+j], rows l0+w*16+n16
    const int qrow = l0 + w * 16 + n16;
    const s8v qA0 = *(const s8v*)&qp[(size_t)qrow * HD + q4 * 8];
    const s8v qA1 = *(const s8v*)&qp[(size_t)qrow * HD + 32 + q4 * 8];

    f4v O[4] = {{0.f,0.f,0.f,0.f},{0.f,0.f,0.f,0.f},{0.f,0.f,0.f,0.f},{0.f,0.f,0.f,0.f}};
    float lrun[4] = {0.f, 0.f, 0.f, 0.f};

    // staging chunk decodes (c = t, t+256)
    int sKey[2], sD0[2], sDd[2];
    #pragma unroll
    for (int cc = 0; cc < 2; cc++) {
        const int c = t + cc * 256;
        const int g = c >> 6;
        const int sT = g >> 1, sS = g & 1;
        const int sQ = (c >> 4) & 3, sN = c & 15;
        sKey[cc] = sT * 16 + sN;
        sD0[cc]  = sS * 32 + sQ * 8;
        sDd[cc]  = sT * 16 + sN;
    }

    const int rowbase = l0 + w * 16 + q4 * 4;   // +r gives the C-layout row
    const int kbase = half * 1152;

    // ---- prologue: tile 0 into registers ----
    s8v kreg[2], vreg[2];
    int mreg[4][4];
    #pragma unroll
    for (int cc = 0; cc < 2; cc++) {
        kreg[cc] = *(const s8v*)&kp[(size_t)(kbase + sKey[cc]) * HD + sD0[cc]];
        vreg[cc] = *(const s8v*)&vp[(size_t)sDd[cc] * L_SEQ + kbase + sD0[cc]];
    }
    #pragma unroll
    for (int t4 = 0; t4 < 4; t4++)
        #pragma unroll
        for (int r = 0; r < 4; r++)
            mreg[t4][r] = mp[(size_t)(rowbase + r) * L_SEQ + kbase + t4 * 16 + n16];

    for (int mt = 0; mt < 18; mt++) {
        const int mb = kbase + mt * 64;
        __syncthreads();   // WAR: previous tile's LDS reads done before restage
        #pragma unroll
        for (int cc = 0; cc < 2; cc++) {
            const int c = t + cc * 256;
            *(s8v*)&Kf[c * 8] = kreg[cc];     // vmcnt satisfied during prev compute
            *(s8v*)&Vf[c * 8] = vreg[cc];
        }
        __syncthreads();

        // ---- issue tile mt+1 loads; latency hides under this tile's compute
        const int mb2 = (mt < 17) ? mb + 64 : mb;   // clamped: always legal
        s8v knx[2], vnx[2];
        int mnx[4][4];
        #pragma unroll
        for (int cc = 0; cc < 2; cc++) {
            knx[cc] = *(const s8v*)&kp[(size_t)(mb2 + sKey[cc]) * HD + sD0[cc]];
            vnx[cc] = *(const s8v*)&vp[(size_t)sDd[cc] * L_SEQ + mb2 + sD0[cc]];
        }
        #pragma unroll
        for (int t4 = 0; t4 < 4; t4++)
            #pragma unroll
            for (int r = 0; r < 4; r++)
                mnx[t4][r] = mp[(size_t)(rowbase + r) * L_SEQ + mb2 + t4 * 16 + n16];

        // S = Q K^T  (C layout: col=lane&15 -> key t4*16+n16, row=q4*4+r)
        f4v S[4];
        #pragma unroll
        for (int t4 = 0; t4 < 4; t4++) {
            const s8v b0 = *(const s8v*)&Kf[((t4 * 2 + 0) * 64 + lane) * 8];
            const s8v b1 = *(const s8v*)&Kf[((t4 * 2 + 1) * 64 + lane) * 8];
            f4v acc = {0.f, 0.f, 0.f, 0.f};
            acc = __builtin_amdgcn_mfma_f32_16x16x32_bf16(qA0, b0, acc, 0, 0, 0);
            acc = __builtin_amdgcn_mfma_f32_16x16x32_bf16(qA1, b1, acc, 0, 0, 0);
            S[t4] = acc;
        }

        // relative positional bias (then mask -> exactly -1e9, matching ref order)
        #pragma unroll
        for (int t4 = 0; t4 < 4; t4++) {
            const int A = (l0 + w * 16) - (mb + t4 * 16);
            if (A >= 47) {
                const float bu = rt[64];
                #pragma unroll
                for (int r = 0; r < 4; r++) S[t4][r] += bu;
            } else if (A <= -47) {
                const float bu = rt[0];
                #pragma unroll
                for (int r = 0; r < 4; r++) S[t4][r] += bu;
            } else {
                #pragma unroll
                for (int r = 0; r < 4; r++) {
                    int dix = A + q4 * 4 + r - n16;
                    dix = min(max(dix, -32), 32) + 32;
                    S[t4][r] += rt[dix];
                }
            }
            #pragma unroll
            for (int r = 0; r < 4; r++)
                if (mreg[t4][r] == 0) S[t4][r] = -1e9f;
        }

        // fixed-max softmax numerator: P = exp(S) (masked -> 0)
        float sum[4] = {0.f, 0.f, 0.f, 0.f};
        #pragma unroll
        for (int r = 0; r < 4; r++) {
            #pragma unroll
            for (int t4 = 0; t4 < 4; t4++) {
                const float p = __expf(S[t4][r]);
                sum[r] += p;
                Pb[w * 1152 + (q4 * 4 + r) * 72 + t4 * 16 + n16] = f2bf(p);
            }
        }

        // O += P V   (per-wave Pb: same-wave dep, no barrier; no rescale)
        const s8v pf0 = *(const s8v*)&Pb[w * 1152 + n16 * 72 + q4 * 8];
        const s8v pf1 = *(const s8v*)&Pb[w * 1152 + n16 * 72 + 32 + q4 * 8];
        #pragma unroll
        for (int t4 = 0; t4 < 4; t4++) {
            f4v o = O[t4];
            const s8v v0 = *(const s8v*)&Vf[((t4 * 2 + 0) * 64 + lane) * 8];
            const s8v v1 = *(const s8v*)&Vf[((t4 * 2 + 1) * 64 + lane) * 8];
            o = __builtin_amdgcn_mfma_f32_16x16x32_bf16(pf0, v0, o, 0, 0, 0);
            o = __builtin_amdgcn_mfma_f32_16x16x32_bf16(pf1, v1, o, 0, 0, 0);
            O[t4] = o;
        }

        // sum reduction AFTER PV — off the MFMA critical path
        #pragma unroll
        for (int r = 0; r < 4; r++) {
            float s = sum[r];
            s += __shfl_xor(s, 1);
            s += __shfl_xor(s, 2);
            s += __shfl_xor(s, 4);
            s += __shfl_xor(s, 8);
            lrun[r] += s;
        }

        // rotate prefetched registers
        #pragma unroll
        for (int cc = 0; cc < 2; cc++) { kreg[cc] = knx[cc]; vreg[cc] = vnx[cc]; }
        #pragma unroll
        for (int t4 = 0; t4 < 4; t4++)
            #pragma unroll
            for (int r = 0; r < 4; r++)
                mreg[t4][r] = mnx[t4][r];
    }

    // write UNNORMALIZED partial O (bf16) in (b, l, c) layout + row sums
    ushort* op = Opart + (size_t)half * PERBL + (size_t)b * L_SEQ * 512;
    #pragma unroll
    for (int r = 0; r < 4; r++) {
        const size_t base = (size_t)(rowbase + r) * 512 + h * 64;
        #pragma unroll
        for (int t4 = 0; t4 < 4; t4++)
            op[base + t4 * 16 + n16] = f2bf(O[t4][r]);
    }
    if (n16 == 0) {
        const size_t sb = (size_t)half * ROWS_TOT + (size_t)bh * L_SEQ;
        #pragma unroll
        for (int r = 0; r < 4; r++)
            Lpart[sb + rowbase + r] = lrun[r];
    }
}

// ==================================================================
// Output projection via bf16 MFMA with the 2-WAY combine fused in
// (R13-proven best): a = bf16((O0 + O1) * f[head]), f = 1/(l0+l1).
// Zero LDS. grid (36, 8, 2), block 256.
__global__ __launch_bounds__(256) void out_mfma(
    const ushort* __restrict__ Opart, const float* __restrict__ Lp,
    const ushort* __restrict__ wf, const float* __restrict__ bo,
    const float* __restrict__ x, float* __restrict__ y)
{
    const int l0 = blockIdx.x * 64;
    const int ob = blockIdx.y;
    const int o0 = ob * 64;
    const int b  = blockIdx.z;
    const int t = threadIdx.x, w = t >> 6, lane = t & 63;
    const int n16 = lane & 15, q4 = lane >> 4;

    const int l = l0 + w * 16 + n16;      // A-row this lane holds

    // per-head normalization scales for this row
    float fsc[8];
    #pragma unroll
    for (int h = 0; h < 8; h++) {
        const size_t s = (size_t)(b * NHEADS + h) * L_SEQ + l;
        fsc[h] = 1.0f / (Lp[s] + Lp[ROWS_TOT + s]);
    }

    const ushort* o0p = Opart + ((size_t)b * L_SEQ + l) * 512 + q4 * 8;
    const ushort* o1p = o0p + PERBL;

    s8v areg[16];
    #pragma unroll
    for (int ks = 0; ks < 16; ks++) {
        const ushort4 a0 = *(const ushort4*)&o0p[ks * 32];
        const ushort4 a1 = *(const ushort4*)&o0p[ks * 32 + 4];
        const ushort4 c0 = *(const ushort4*)&o1p[ks * 32];
        const ushort4 c1 = *(const ushort4*)&o1p[ks * 32 + 4];
        const float f = fsc[ks >> 1];     // head = (ks*32+q4*8)>>6 = ks>>1
        s8v a;
        a[0] = (short)f2bf((bf2f(a0.x) + bf2f(c0.x)) * f);
        a[1] = (short)f2bf((bf2f(a0.y) + bf2f(c0.y)) * f);
        a[2] = (short)f2bf((bf2f(a0.z) + bf2f(c0.z)) * f);
        a[3] = (short)f2bf((bf2f(a0.w) + bf2f(c0.w)) * f);
        a[4] = (short)f2bf((bf2f(a1.x) + bf2f(c1.x)) * f);
        a[5] = (short)f2bf((bf2f(a1.y) + bf2f(c1.y)) * f);
        a[6] = (short)f2bf((bf2f(a1.z) + bf2f(c1.z)) * f);
        a[7] = (short)f2bf((bf2f(a1.w) + bf2f(c1.w)) * f);
        areg[ks] = a;
    }

    const size_t lb = (size_t)lane * 8;

    f4v acc[4] = {{0.f,0.f,0.f,0.f},{0.f,0.f,0.f,0.f},{0.f,0.f,0.f,0.f},{0.f,0.f,0.f,0.f}};
    for (int ks = 0; ks < 16; ks++) {
        s8v bf[4];
        #pragma unroll
        for (int t4 = 0; t4 < 4; t4++)
            bf[t4] = *(const s8v*)&wf[
                ((size_t)((3 * 8 + ob) * 64 + ks * 4 + t4)) * 512 + lb];
        const s8v a = areg[ks];
        #pragma unroll
        for (int t4 = 0; t4 < 4; t4++)
            acc[t4] = __builtin_amdgcn_mfma_f32_16x16x32_bf16(a, bf[t4], acc[t4], 0, 0, 0);
    }

    const int rowbase = l0 + w * 16 + q4 * 4;
    #pragma unroll
    for (int t4 = 0; t4 < 4; t4++) {
        const int o = o0 + t4 * 16 + n16;
        const float bi = bo[o];
        const size_t off = ((size_t)b * CDIM + o) * L_SEQ + rowbase;
        const float4 xv = *(const float4*)&x[off];
        float4 st;
        st.x = acc[t4][0] + bi + xv.x;
        st.y = acc[t4][1] + bi + xv.y;
        st.z = acc[t4][2] + bi + xv.z;
        st.w = acc[t4][3] + bi + xv.w;
        *(float4*)&y[off] = st;
    }
}

// ==================================================================
// LayerNorm over channels. 144 blocks, 32 positions/block (128 B
// coalesced segments), 8 channel-groups x 64 channels.
__global__ __launch_bounds__(256) void ln_kernel(
    float* __restrict__ y, const float* __restrict__ gamma,
    const float* __restrict__ beta)
{
    const int t = threadIdx.x;
    const int p = t & 31;         // position within block
    const int g = t >> 5;         // channel group: 8 groups x 64 ch
    const int pos = blockIdx.x * 32 + p;
    const int b = (pos >= L_SEQ) ? 1 : 0;
    const int l = pos - b * L_SEQ;
    float* col = y + (size_t)b * CDIM * L_SEQ + l;

    float s = 0.f, sq = 0.f;
    for (int c = g * 64; c < g * 64 + 64; c++) {
        const float v = col[(size_t)c * L_SEQ];
        s += v; sq += v * v;
    }
    __shared__ float S1[8][32];
    __shared__ float S2[8][32];
    S1[g][p] = s; S2[g][p] = sq;
    __syncthreads();
    if (t < 32) {
        float ss = 0.f, qq = 0.f;
        #pragma unroll
        for (int gg = 0; gg < 8; gg++) { ss += S1[gg][t]; qq += S2[gg][t]; }
        const float mu = ss * (1.0f / CDIM);
        const float var = qq * (1.0f / CDIM) - mu * mu;
        S1[0][t] = mu;
        S2[0][t] = rsqrtf(var + 1e-5f);
    }
    __syncthreads();
    const float mu = S1[0][p];
    const float rs = S2[0][p];
    for (int c = g * 64; c < g * 64 + 64; c++) {
        const float v = col[(size_t)c * L_SEQ];
        col[(size_t)c * L_SEQ] = (v - mu) * rs * gamma[c] + beta[c];
    }
}

// ==================================================================
extern "C" void kernel_launch(void* const* d_in, const int* in_sizes, int n_in,
                              void* d_out, int out_size, void* d_ws, size_t ws_size,
                              hipStream_t stream) {
    const float* x    = (const float*)d_in[0];
    const int* mask   = (const int*)d_in[1];
    const float* pos  = (const float*)d_in[2];
    const float* Wq   = (const float*)d_in[3];
    const float* bq   = (const float*)d_in[4];
    const float* Wk   = (const float*)d_in[5];
    const float* bk   = (const float*)d_in[6];
    const float* Wv   = (const float*)d_in[7];
    const float* bv   = (const float*)d_in[8];
    const float* Wo   = (const float*)d_in[9];
    const float* bo   = (const float*)d_in[10];
    const float* rel  = (const float*)d_in[11];
    const float* gam  = (const float*)d_in[12];
    const float* bet  = (const float*)d_in[13];

    // workspace layout (30.7 MB):
    //   qw/kw/vw  3*PERBL ushort = 14.16 MB
    //   xtw         PERBL ushort =  4.72 MB
    //   wbw     4*512*512 ushort =  2.10 MB  (fragment-major weights)
    //   Opart     2*PERBL ushort =  9.44 MB  (bf16 partials, 2 key-halves)
    //   Lpart   2*ROWS_TOT f32   =  0.29 MB
    ushort* qw  = (ushort*)d_ws;
    ushort* kw  = qw + PERBL;
    ushort* vw  = kw + PERBL;
    ushort* xtw = vw + PERBL;
    ushort* wbw = xtw + PERBL;
    ushort* Opart = wbw + (size_t)4 * 262144;
    float* Lpart = (float*)(Opart + 2 * PERBL);
    float* y = (float*)d_out;

    prep<<<dim3(512 + 576), 256, 0, stream>>>(Wq, Wk, Wv, Wo, x, pos, wbw, xtw);

    qkv_mfma<<<dim3(L_SEQ / 64, CDIM / 64, 2), 256, 0, stream>>>(
        xtw, wbw, bq, bk, bv, qw, kw, vw);

    flash_attn_mfma<<<dim3(1152), 256, 0, stream>>>(qw, kw, vw, mask, rel,
                                                    Opart, Lpart);

    out_mfma<<<dim3(L_SEQ / 64, CDIM / 64, 2), 256, 0, stream>>>(
        Opart, Lpart, wbw, bo, x, y);

    ln_kernel<<<(2 * L_SEQ) / 32, 256, 0, stream>>>(y, gam, bet);
}